// Round 1
// baseline (1266.009 us; speedup 1.0000x reference)
//
#include <hip/hip_runtime.h>
#include <hip/hip_bf16.h>

#define B_ 16384
#define F_ 39
#define V_ 100000
#define D_ 64
#define H_ 400
#define IN_ 2496
#define NP_ 512

typedef __attribute__((ext_vector_type(8))) short short8;
typedef __attribute__((ext_vector_type(4))) float f32x4;

__device__ __forceinline__ void gload_lds16(const void* g, void* l) {
  __builtin_amdgcn_global_load_lds((const __attribute__((address_space(1))) unsigned int*)g,
                                   (__attribute__((address_space(3))) unsigned int*)l, 16, 0, 0);
}

// ---- transpose + pad to bf16: dst[n][k] = src[k][n] (n<Nsrc,k<Ksrc), else 0 ----
__global__ __launch_bounds__(1024) void transpose_pad(const float* __restrict__ src,
                                                      __hip_bfloat16* __restrict__ dst,
                                                      int Ksrc, int Nsrc, int Kpad) {
  __shared__ float sh[32][33];
  int tx = threadIdx.x, ty = threadIdx.y;
  int k0 = blockIdx.x * 32, n0 = blockIdx.y * 32;
  int k = k0 + ty, n = n0 + tx;
  sh[ty][tx] = (k < Ksrc && n < Nsrc) ? src[(size_t)k * Nsrc + n] : 0.f;
  __syncthreads();
  dst[(size_t)(n0 + ty) * Kpad + k0 + tx] = __float2bfloat16(sh[tx][ty]);
}

__global__ __launch_bounds__(512) void prep_pads(const float* __restrict__ b1, const float* __restrict__ b2,
                                                 const float* __restrict__ b3, const float* __restrict__ w4,
                                                 float* __restrict__ b1p, float* __restrict__ b2p,
                                                 float* __restrict__ b3p, float* __restrict__ w4p) {
  int i = threadIdx.x;
  b1p[i] = (i < H_) ? b1[i] : 0.f;
  b2p[i] = (i < H_) ? b2[i] : 0.f;
  b3p[i] = (i < H_) ? b3[i] : 0.f;
  w4p[i] = (i < H_) ? w4[i] : 0.f;
}

// ---- gather + fwfm (one wave per sample; lane = d) ----
__global__ __launch_bounds__(256) void gather_fwfm(const int* __restrict__ x, const float* __restrict__ embs,
                                                   const float* __restrict__ fc, const float* __restrict__ lin,
                                                   __hip_bfloat16* __restrict__ flat, float* __restrict__ base) {
  __shared__ float wsym[F_ * F_];
  __shared__ float lins[F_ * D_];
  int tid = threadIdx.x;
  for (int i = tid; i < F_ * F_; i += 256) {
    int k = i / F_, j = i % F_;
    wsym[i] = 0.5f * (fc[i] + fc[j * F_ + k]);
  }
  for (int i = tid; i < F_ * D_; i += 256) lins[i] = lin[i];
  __syncthreads();
  int l = tid & 63, w = tid >> 6;
  int b = blockIdx.x * 4 + w;
  const int* xr = x + b * F_;
  float e[F_];
#pragma unroll
  for (int f = 0; f < F_; ++f) {
    int idx = xr[f];
    e[f] = embs[((size_t)(f * V_ + idx)) * D_ + l];
  }
  float first = 0.f, self = 0.f, quad = 0.f;
#pragma unroll
  for (int k = 0; k < F_; ++k) {
    float yk = 0.f;
#pragma unroll
    for (int j = 0; j < F_; ++j) yk = fmaf(wsym[k * F_ + j], e[j], yk);
    quad  = fmaf(yk, e[k], quad);
    self  = fmaf(e[k], e[k], self);
    first = fmaf(e[k], lins[k * D_ + l], first);
  }
  float p = first + 0.5f * (quad - self);
#pragma unroll
  for (int off = 32; off > 0; off >>= 1) p += __shfl_xor(p, off, 64);
  if (l == 0) base[b] = p;
#pragma unroll
  for (int f = 0; f < F_; ++f)
    flat[(size_t)b * IN_ + f * D_ + l] = __float2bfloat16(e[f]);
}

// ---- m97-style bf16 GEMM: C[M,512] = relu(A[M,K] @ Bt[512,K]^T + bias) ----
__global__ __launch_bounds__(256) void gemm_bt_relu(const short* __restrict__ A, const short* __restrict__ Bt,
                                                    const float* __restrict__ bias,
                                                    __hip_bfloat16* __restrict__ C, int K) {
  __shared__ short As[128 * 32];
  __shared__ short Bs[128 * 32];
  int tid = threadIdx.x;
  int l = tid & 63, w = tid >> 6;
  int wr = (w >> 1) * 64, wc = (w & 1) * 64;
  int m0 = blockIdx.x * 128, n0 = blockIdx.y * 128;
  f32x4 acc[4][4];
  f32x4 z = {0.f, 0.f, 0.f, 0.f};
#pragma unroll
  for (int m = 0; m < 4; ++m)
#pragma unroll
    for (int n = 0; n < 4; ++n) acc[m][n] = z;
  int nkt = K >> 5;
  int lr = l & 15, lkb = (l >> 4) * 8;
  for (int kt = 0; kt < nkt; ++kt) {
#pragma unroll
    for (int i = 0; i < 2; ++i) {
      int idx = i * 256 + tid;
      int r = idx >> 2, c = idx & 3;
      const short* ga = A + (size_t)(m0 + r) * K + kt * 32 + c * 8;
      const short* gb = Bt + (size_t)(n0 + r) * K + kt * 32 + c * 8;
      int lb = (i * 256 + (tid & ~63)) * 8;
      gload_lds16(ga, As + lb);
      gload_lds16(gb, Bs + lb);
    }
    __syncthreads();
    short8 af[4], bfr[4];
#pragma unroll
    for (int m = 0; m < 4; ++m) af[m] = *(const short8*)(As + (wr + m * 16 + lr) * 32 + lkb);
#pragma unroll
    for (int n = 0; n < 4; ++n) bfr[n] = *(const short8*)(Bs + (wc + n * 16 + lr) * 32 + lkb);
#pragma unroll
    for (int m = 0; m < 4; ++m)
#pragma unroll
      for (int n = 0; n < 4; ++n)
        acc[m][n] = __builtin_amdgcn_mfma_f32_16x16x32_bf16(af[m], bfr[n], acc[m][n], 0, 0, 0);
    __syncthreads();
  }
#pragma unroll
  for (int n = 0; n < 4; ++n) {
    int gc = n0 + wc + n * 16 + lr;
    float bv = bias[gc];
#pragma unroll
    for (int m = 0; m < 4; ++m) {
      int gr0 = m0 + wr + m * 16 + (l >> 4) * 4;
#pragma unroll
      for (int r = 0; r < 4; ++r) {
        float v = acc[m][n][r] + bv;
        v = fmaxf(v, 0.f);
        C[(size_t)(gr0 + r) * NP_ + gc] = __float2bfloat16(v);
      }
    }
  }
}

// ---- final: out = sigmoid(base + h3 @ w4 + b4) ----
__global__ __launch_bounds__(256) void final_k(const __hip_bfloat16* __restrict__ h3, const float* __restrict__ w4p,
                                               const float* __restrict__ base, const float* __restrict__ b4,
                                               float* __restrict__ out) {
  int tid = threadIdx.x;
  int l = tid & 63, w = tid >> 6;
  int b = blockIdx.x * 4 + w;
  const __hip_bfloat16* hr = h3 + (size_t)b * NP_;
  float s = 0.f;
#pragma unroll
  for (int j = 0; j < 8; ++j)
    s = fmaf(__bfloat162float(hr[j * 64 + l]), w4p[j * 64 + l], s);
#pragma unroll
  for (int off = 32; off > 0; off >>= 1) s += __shfl_xor(s, off, 64);
  if (l == 0) {
    float zv = s + base[b] + b4[0];
    out[b] = 1.f / (1.f + expf(-zv));
  }
}

extern "C" void kernel_launch(void* const* d_in, const int* in_sizes, int n_in,
                              void* d_out, int out_size, void* d_ws, size_t ws_size,
                              hipStream_t stream) {
  const int*   x    = (const int*)d_in[0];
  const float* embs = (const float*)d_in[1];
  const float* fc   = (const float*)d_in[2];
  const float* lin  = (const float*)d_in[3];
  const float* w1   = (const float*)d_in[4];
  const float* b1   = (const float*)d_in[5];
  const float* w2   = (const float*)d_in[6];
  const float* b2   = (const float*)d_in[7];
  const float* w3   = (const float*)d_in[8];
  const float* b3   = (const float*)d_in[9];
  const float* w4   = (const float*)d_in[10];
  const float* b4   = (const float*)d_in[11];
  float* out = (float*)d_out;

  char* p = (char*)d_ws;
  size_t off = 0;
  auto carve = [&](size_t bytes) -> char* {
    char* r = p + off;
    off += (bytes + 255) & ~(size_t)255;
    return r;
  };
  __hip_bfloat16* flat = (__hip_bfloat16*)carve((size_t)B_ * IN_ * 2);
  __hip_bfloat16* w1t  = (__hip_bfloat16*)carve((size_t)NP_ * IN_ * 2);
  __hip_bfloat16* w2t  = (__hip_bfloat16*)carve((size_t)NP_ * NP_ * 2);
  __hip_bfloat16* w3t  = (__hip_bfloat16*)carve((size_t)NP_ * NP_ * 2);
  __hip_bfloat16* h1   = (__hip_bfloat16*)carve((size_t)B_ * NP_ * 2);
  __hip_bfloat16* h2   = (__hip_bfloat16*)carve((size_t)B_ * NP_ * 2);
  __hip_bfloat16* h3   = (__hip_bfloat16*)carve((size_t)B_ * NP_ * 2);
  float* base = (float*)carve((size_t)B_ * 4);
  float* b1p  = (float*)carve(NP_ * 4);
  float* b2p  = (float*)carve(NP_ * 4);
  float* b3p  = (float*)carve(NP_ * 4);
  float* w4p  = (float*)carve(NP_ * 4);

  hipLaunchKernelGGL(transpose_pad, dim3(IN_ / 32, NP_ / 32), dim3(32, 32), 0, stream, w1, w1t, IN_, H_, IN_);
  hipLaunchKernelGGL(transpose_pad, dim3(NP_ / 32, NP_ / 32), dim3(32, 32), 0, stream, w2, w2t, H_, H_, NP_);
  hipLaunchKernelGGL(transpose_pad, dim3(NP_ / 32, NP_ / 32), dim3(32, 32), 0, stream, w3, w3t, H_, H_, NP_);
  hipLaunchKernelGGL(prep_pads, dim3(1), dim3(NP_), 0, stream, b1, b2, b3, w4, b1p, b2p, b3p, w4p);
  hipLaunchKernelGGL(gather_fwfm, dim3(B_ / 4), dim3(256), 0, stream, x, embs, fc, lin, flat, base);
  hipLaunchKernelGGL(gemm_bt_relu, dim3(B_ / 128, NP_ / 128), dim3(256), 0, stream,
                     (const short*)flat, (const short*)w1t, b1p, h1, IN_);
  hipLaunchKernelGGL(gemm_bt_relu, dim3(B_ / 128, NP_ / 128), dim3(256), 0, stream,
                     (const short*)h1, (const short*)w2t, b2p, h2, NP_);
  hipLaunchKernelGGL(gemm_bt_relu, dim3(B_ / 128, NP_ / 128), dim3(256), 0, stream,
                     (const short*)h2, (const short*)w3t, b3p, h3, NP_);
  hipLaunchKernelGGL(final_k, dim3(B_ / 4), dim3(256), 0, stream, h3, w4p, base, b4, out);
}